// Round 6
// baseline (118.524 us; speedup 1.0000x reference)
//
#include <hip/hip_runtime.h>

constexpr int QQ = 100;

using short8 = __attribute__((ext_vector_type(8))) short;
using f32x4  = __attribute__((ext_vector_type(4))) float;

__device__ inline unsigned short f2bf(float f) {
    unsigned u = __float_as_uint(f);
    return (unsigned short)((u + 0x7FFF + ((u >> 16) & 1)) >> 16);
}
__device__ inline float bf2f(unsigned short us) {
    return __uint_as_float(((unsigned)us) << 16);
}

// ---------------- K0: prep ----------------
// blocks 0..511: x -> xt (bf16, [b][px][c]); 512..623: weight fold -> weffR
// (fragment-major); 624: beff + wproj -> wpbR (fragment-major)
__global__ __launch_bounds__(256)
void k_prep(const float* __restrict__ x, const float* __restrict__ we,
            const float* __restrict__ wc, const float* __restrict__ be,
            const float* __restrict__ bc, const float* __restrict__ wproj,
            unsigned short* __restrict__ xt, unsigned short* __restrict__ weffR,
            float* __restrict__ beff, unsigned short* __restrict__ wpbR) {
    __shared__ float smf[2880];   // 11.5 KB; x2bf path uses it as shorts
    int blk = blockIdx.x, tid = threadIdx.x;
    if (blk < 512) {
        unsigned short* t = (unsigned short*)smf;   // [64 px][pitch 40] shorts
        int b = blk >> 8, y = (blk >> 2) & 63, cq = blk & 3;
        int lx = tid & 63, cg = tid >> 6;
        const float* xb = x + (b * 128 + cq * 32 + cg * 8) * 4096 + y * 64 + lx;
#pragma unroll
        for (int i = 0; i < 8; ++i)
            t[lx * 40 + cg * 8 + i] = f2bf(xb[i * 4096]);
        __syncthreads();
        int px = tid >> 2, j = tid & 3;
        *(short8*)(xt + (b * 4096 + y * 64 + px) * 128 + cq * 32 + j * 8)
            = *(const short8*)(t + px * 40 + j * 8);
        return;
    }
    if (blk < 624) {
        int q = blk - 512;            // 0..111 (>=100: zero-fill)
        float* we_s = smf;            // 576
        float* red  = smf + 576;      // 18*128
        if (q < QQ) {
            for (int idx = tid; idx < 576; idx += 256) we_s[idx] = we[q * 576 + idx];
            __syncthreads();
            int c = tid & 127, mh = tid >> 7;
            float acc[9];
#pragma unroll
            for (int k = 0; k < 9; ++k) acc[k] = 0.f;
            for (int m = 0; m < 32; ++m) {
                int mm = mh * 32 + m;
                float wv = wc[mm * 128 + c];
#pragma unroll
                for (int k = 0; k < 9; ++k) acc[k] += we_s[mm * 9 + k] * wv;
            }
#pragma unroll
            for (int k = 0; k < 9; ++k) red[(mh * 9 + k) * 128 + c] = acc[k];
            __syncthreads();
        }
        int mf = q >> 4, l15 = q & 15;
        for (int idx = tid; idx < 1152; idx += 256) {
            int kap = idx >> 7, r = idx & 127;
            float v = (q < QQ) ? (red[kap * 128 + r] + red[(9 + kap) * 128 + r]) : 0.f;
            int c32 = r >> 5, kgrp = (r >> 3) & 3, j = r & 7;
            weffR[(((kap * 4 + c32) * 7 + mf) * 64 + kgrp * 16 + l15) * 8 + j] = f2bf(v);
        }
        return;
    }
    // blk == 624: beff + wpbR
    if (tid < 128) {
        float s = 0.f;
        if (tid < QQ) {
            s = be[tid];
            for (int m = 0; m < 64; ++m) {
                float t2 = 0.f;
#pragma unroll
                for (int k = 0; k < 9; ++k) t2 += we[(tid * 64 + m) * 9 + k];
                s += t2 * bc[m];
            }
        }
        beff[tid] = s;
    }
    for (int idx = tid; idx < 16384; idx += 256) {
        int o = idx >> 7, c = idx & 127;
        int cs = c >> 5, kgrp = (c >> 3) & 3, j = c & 7;
        int mf = o >> 4, l15 = o & 15;
        wpbR[((cs * 8 + mf) * 64 + kgrp * 16 + l15) * 8 + j] = f2bf(wproj[idx]);
    }
}

// ---------------- K1: fused enc + softmax + reassembly + projection ----------------
// grid = 2 b x 32 ty x 8 tx = 512 blocks, 256 thr. M-split enc (no psum): wave w
// owns q-fragments {2w, 2w+1} (wave 3: {6}) over the FULL K=1152, writes sm direct.
__global__ __launch_bounds__(256)
void k_main(const unsigned short* __restrict__ xt, const unsigned short* __restrict__ weffR,
            const float* __restrict__ beff, const unsigned short* __restrict__ wpbR,
            const float* __restrict__ bproj, float* __restrict__ out) {
    __shared__ __align__(16) char smem[43392];
    unsigned short* xs = (unsigned short*)smem;            // [72 px][136] shorts, 19584 B
    float* sm          = (float*)(smem + 19584);           // [25 k][64 e], 6400 B
    unsigned short* re = (unsigned short*)(smem + 25984);  // [64 p][136] shorts, 17408 B

    int bid = blockIdx.x;
    int b = bid >> 8, rem = bid & 255;
    int ty = rem >> 3, tx = rem & 7;
    int tid = threadIdx.x;
    int lane = tid & 63, w = tid >> 6;
    int l15 = lane & 15, kgrp = lane >> 4;
    int fb = w * 2;
    int nf = (w < 3) ? 2 : 1;

    // hoisted bias loads (overlap with staging)
    float bq[2][4];
#pragma unroll
    for (int j = 0; j < 2; ++j)
#pragma unroll
        for (int r = 0; r < 4; ++r) {
            int q = (fb + j) * 16 + kgrp * 4 + r;   // <= 127, beff has 128 entries
            bq[j][r] = beff[q];
        }

    // ---- phase 1: stage 6x12 low-res halo x 128c (serves enc conv AND reassembly)
    int R0 = ty * 2 - 2, C0 = tx * 8 - 2;
    for (int idx = tid; idx < 576; idx += 256) {
        int hp = idx >> 3, cq = idx & 7;
        int hy = hp / 12, hx = hp - hy * 12;
        int gr = R0 + hy, gc = C0 + hx;
        short8 v0 = {0,0,0,0,0,0,0,0}, v1 = {0,0,0,0,0,0,0,0};
        if ((unsigned)gr < 64u && (unsigned)gc < 64u) {
            const unsigned short* src = xt + (b * 4096 + gr * 64 + gc) * 128 + cq * 16;
            v0 = *(const short8*)src;
            v1 = *(const short8*)(src + 8);
        }
        *(short8*)&xs[hp * 136 + cq * 16]     = v0;
        *(short8*)&xs[hp * 136 + cq * 16 + 8] = v1;
    }
    __syncthreads();

    // ---- phase 2: encoder GEMM, M-split (full K per wave)
    int ly = l15 >> 3, lx = l15 & 7;
    f32x4 acc[2];
    acc[0] = f32x4{0.f, 0.f, 0.f, 0.f};
    acc[1] = f32x4{0.f, 0.f, 0.f, 0.f};
#pragma unroll
    for (int kap = 0; kap < 9; ++kap) {
        int dy = kap / 3, dx = kap % 3;
        const unsigned short* xrow = &xs[((ly + dy + 1) * 12 + lx + dx + 1) * 136];
#pragma unroll
        for (int cs = 0; cs < 4; ++cs) {
            short8 bfrag = *(const short8*)&xrow[cs * 32 + kgrp * 8];
            const unsigned short* wrk = weffR + ((kap * 4 + cs) * 7 + fb) * 512 + lane * 8;
            acc[0] = __builtin_amdgcn_mfma_f32_16x16x32_bf16(
                *(const short8*)wrk, bfrag, acc[0], 0, 0, 0);
            if (w < 3)
                acc[1] = __builtin_amdgcn_mfma_f32_16x16x32_bf16(
                    *(const short8*)(wrk + 512), bfrag, acc[1], 0, 0, 0);
        }
    }
    // ---- phase 3: write logits + bias directly to sm
#pragma unroll
    for (int j = 0; j < 2; ++j) {
        if (j < nf) {
            int f = fb + j;
#pragma unroll
            for (int r = 0; r < 4; ++r) {
                int q = f * 16 + kgrp * 4 + r;
                if (q < QQ)
                    sm[(q >> 2) * 64 + l15 * 4 + (q & 3)] = acc[j][r] + bq[j][r];
            }
        }
    }
    __syncthreads();

    // ---- phase 4: wave-parallel softmax over 25 k
    {
        int e = tid >> 2, kg = tid & 3;
        float v[7];
        float m = -1e30f;
#pragma unroll
        for (int j = 0; j < 7; ++j) {
            int k = kg + 4 * j;
            float val = (k < 25) ? sm[k * 64 + e] : -1e30f;
            v[j] = val; m = fmaxf(m, val);
        }
        m = fmaxf(m, __shfl_xor(m, 1));
        m = fmaxf(m, __shfl_xor(m, 2));
        float s = 0.f;
#pragma unroll
        for (int j = 0; j < 7; ++j) {
            int k = kg + 4 * j;
            if (k < 25) { v[j] = __expf(v[j] - m); s += v[j]; }
        }
        s += __shfl_xor(s, 1);
        s += __shfl_xor(s, 2);
        float inv = 1.f / s;
#pragma unroll
        for (int j = 0; j < 7; ++j) {
            int k = kg + 4 * j;
            if (k < 25) sm[k * 64 + e] = v[j] * inv;
        }
    }
    __syncthreads();

    // ---- phase 5: reassembly -> re (bf16, [p][136])
    {
        int lowpx = tid & 15, cgrp = tid >> 4;
        int ly2 = lowpx >> 3, lx2 = lowpx & 7;
        float racc[8][4];
#pragma unroll
        for (int cc = 0; cc < 8; ++cc)
#pragma unroll
            for (int s = 0; s < 4; ++s) racc[cc][s] = 0.f;
#pragma unroll
        for (int k = 0; k < 25; ++k) {
            int i = k / 5, j = k % 5;
            float4 wk4 = *(const float4*)&sm[k * 64 + lowpx * 4];
            short8 tap8 = *(const short8*)&xs[((ly2 + i) * 12 + (lx2 + j)) * 136 + cgrp * 8];
#pragma unroll
            for (int cc = 0; cc < 8; ++cc) {
                float tap = bf2f((unsigned short)tap8[cc]);
                racc[cc][0] += wk4.x * tap;
                racc[cc][1] += wk4.y * tap;
                racc[cc][2] += wk4.z * tap;
                racc[cc][3] += wk4.w * tap;
            }
        }
#pragma unroll
        for (int s = 0; s < 4; ++s) {
            int p = (ly2 * 2 + (s >> 1)) * 16 + lx2 * 2 + (s & 1);
            short8 pk;
#pragma unroll
            for (int cc = 0; cc < 8; ++cc) pk[cc] = (short)f2bf(racc[cc][s]);
            *(short8*)&re[p * 136 + cgrp * 8] = pk;
        }
    }
    __syncthreads();

    // ---- phase 6: projection GEMM (M=128 o, N=64 p, K=128 c); wave w owns n-frag w
    f32x4 pacc[8];
#pragma unroll
    for (int mf = 0; mf < 8; ++mf) pacc[mf] = f32x4{0.f, 0.f, 0.f, 0.f};
#pragma unroll
    for (int cs = 0; cs < 4; ++cs) {
        short8 bfrag = *(const short8*)&re[(w * 16 + l15) * 136 + cs * 32 + kgrp * 8];
        const unsigned short* wrp = wpbR + (cs * 8) * 512 + lane * 8;
#pragma unroll
        for (int mf = 0; mf < 8; ++mf) {
            short8 af = *(const short8*)(wrp + mf * 512);
            pacc[mf] = __builtin_amdgcn_mfma_f32_16x16x32_bf16(af, bfrag, pacc[mf], 0, 0, 0);
        }
    }
    // ---- phase 7: store (16 consecutive ws per quarter-wave)
    int hs = ty * 4 + w, ws = tx * 16 + l15;
    float* ob = out + (b * 128) * 16384 + hs * 128 + ws;
#pragma unroll
    for (int mf = 0; mf < 8; ++mf)
#pragma unroll
        for (int r = 0; r < 4; ++r) {
            int o = mf * 16 + kgrp * 4 + r;
            ob[o * 16384] = pacc[mf][r] + bproj[o];
        }
}

extern "C" void kernel_launch(void* const* d_in, const int* in_sizes, int n_in,
                              void* d_out, int out_size, void* d_ws, size_t ws_size,
                              hipStream_t stream) {
    const float* x      = (const float*)d_in[0];
    const float* w_comp = (const float*)d_in[1];
    const float* b_comp = (const float*)d_in[2];
    const float* w_enc  = (const float*)d_in[3];
    const float* b_enc  = (const float*)d_in[4];
    const float* w_proj = (const float*)d_in[5];
    const float* b_proj = (const float*)d_in[6];
    float* out = (float*)d_out;

    char* base = (char*)d_ws;
    unsigned short* xt    = (unsigned short*)(base);              // 2,097,152 B
    unsigned short* weffR = (unsigned short*)(base + 2097152);    //   258,048 B (252*512*2)
    float*          beff  = (float*)         (base + 2355200);    //       512 B (128 f32)
    unsigned short* wpbR  = (unsigned short*)(base + 2355712);    //    32,768 B

    k_prep<<<625, 256, 0, stream>>>(x, w_enc, w_comp, b_enc, b_comp, w_proj,
                                    xt, weffR, beff, wpbR);
    k_main<<<512, 256, 0, stream>>>(xt, weffR, beff, wpbR, b_proj, out);
}

// Round 7
// 107.529 us; speedup vs baseline: 1.1023x; 1.1023x over previous
//
#include <hip/hip_runtime.h>

constexpr int QQ = 100;

using short8  = __attribute__((ext_vector_type(8))) short;
using short4v = __attribute__((ext_vector_type(4))) short;
using f32x4   = __attribute__((ext_vector_type(4))) float;

__device__ inline unsigned short f2bf(float f) {
    unsigned u = __float_as_uint(f);
    return (unsigned short)((u + 0x7FFF + ((u >> 16) & 1)) >> 16);
}
__device__ inline float bf2f(unsigned short us) {
    return __uint_as_float(((unsigned)us) << 16);
}

// ---------------- K0: prep ----------------
// blocks 0..511: x -> xt (bf16, [b][px][c]); 512..623: weight fold -> weffR
// (fragment-major); 624: beff + wproj -> wpbR (fragment-major)
__global__ __launch_bounds__(256)
void k_prep(const float* __restrict__ x, const float* __restrict__ we,
            const float* __restrict__ wc, const float* __restrict__ be,
            const float* __restrict__ bc, const float* __restrict__ wproj,
            unsigned short* __restrict__ xt, unsigned short* __restrict__ weffR,
            float* __restrict__ beff, unsigned short* __restrict__ wpbR) {
    __shared__ float smf[2880];   // 11.5 KB; x2bf path uses it as shorts
    int blk = blockIdx.x, tid = threadIdx.x;
    if (blk < 512) {
        unsigned short* t = (unsigned short*)smf;   // [64 px][pitch 40] shorts
        int b = blk >> 8, y = (blk >> 2) & 63, cq = blk & 3;
        int lx = tid & 63, cg = tid >> 6;
        const float* xb = x + (b * 128 + cq * 32 + cg * 8) * 4096 + y * 64 + lx;
#pragma unroll
        for (int i = 0; i < 8; ++i)
            t[lx * 40 + cg * 8 + i] = f2bf(xb[i * 4096]);
        __syncthreads();
        int px = tid >> 2, j = tid & 3;
        *(short8*)(xt + (b * 4096 + y * 64 + px) * 128 + cq * 32 + j * 8)
            = *(const short8*)(t + px * 40 + j * 8);
        return;
    }
    if (blk < 624) {
        int q = blk - 512;            // 0..111 (>=100: zero-fill)
        float* we_s = smf;            // 576
        float* red  = smf + 576;      // 18*128
        if (q < QQ) {
            for (int idx = tid; idx < 576; idx += 256) we_s[idx] = we[q * 576 + idx];
            __syncthreads();
            int c = tid & 127, mh = tid >> 7;
            float acc[9];
#pragma unroll
            for (int k = 0; k < 9; ++k) acc[k] = 0.f;
            for (int m = 0; m < 32; ++m) {
                int mm = mh * 32 + m;
                float wv = wc[mm * 128 + c];
#pragma unroll
                for (int k = 0; k < 9; ++k) acc[k] += we_s[mm * 9 + k] * wv;
            }
#pragma unroll
            for (int k = 0; k < 9; ++k) red[(mh * 9 + k) * 128 + c] = acc[k];
            __syncthreads();
        }
        int mf = q >> 4, l15 = q & 15;
        for (int idx = tid; idx < 1152; idx += 256) {
            int kap = idx >> 7, r = idx & 127;
            float v = (q < QQ) ? (red[kap * 128 + r] + red[(9 + kap) * 128 + r]) : 0.f;
            int c32 = r >> 5, kgrp = (r >> 3) & 3, j = r & 7;
            weffR[(((kap * 4 + c32) * 7 + mf) * 64 + kgrp * 16 + l15) * 8 + j] = f2bf(v);
        }
        return;
    }
    // blk == 624: beff + wpbR
    if (tid < 128) {
        float s = 0.f;
        if (tid < QQ) {
            s = be[tid];
            for (int m = 0; m < 64; ++m) {
                float t2 = 0.f;
#pragma unroll
                for (int k = 0; k < 9; ++k) t2 += we[(tid * 64 + m) * 9 + k];
                s += t2 * bc[m];
            }
        }
        beff[tid] = s;
    }
    for (int idx = tid; idx < 16384; idx += 256) {
        int o = idx >> 7, c = idx & 127;
        int cs = c >> 5, kgrp = (c >> 3) & 3, j = c & 7;
        int mf = o >> 4, l15 = o & 15;
        wpbR[((cs * 8 + mf) * 64 + kgrp * 16 + l15) * 8 + j] = f2bf(wproj[idx]);
    }
}

// ---------------- K1: fused enc + softmax + reassembly + projection ----------------
// grid = 2 b x 32 ty x 8 tx = 512 blocks, 512 thr (8 waves -> 16 waves/CU).
// enc split M x K across waves: wave w = (mg = w>>1 owns m-frags {2mg,2mg+1},
// kp = w&1 owns K-half cs {2kp, 2kp+1}); 2-way psum reduce in LDS (aliases re).
__global__ __launch_bounds__(512)
void k_main(const unsigned short* __restrict__ xt, const unsigned short* __restrict__ weffR,
            const float* __restrict__ beff, const unsigned short* __restrict__ wpbR,
            const float* __restrict__ bproj, float* __restrict__ out) {
    __shared__ __align__(16) char smem[43392];
    unsigned short* xs = (unsigned short*)smem;            // [72 px][136] shorts, 19584 B
    float* sm          = (float*)(smem + 19584);           // [25 k][64 e], 6400 B
    float* psum        = (float*)(smem + 25984);           // [2 kp][112 q][17], 15232 B
    unsigned short* re = (unsigned short*)(smem + 25984);  // [64 p][136] shorts (aliases psum)

    int bid = blockIdx.x;
    int b = bid >> 8, rem = bid & 255;
    int ty = rem >> 3, tx = rem & 7;
    int tid = threadIdx.x;
    int lane = tid & 63, w = tid >> 6;
    int l15 = lane & 15, kgrp = lane >> 4;

    // ---- phase 1: stage 6x12 low-res halo x 128c (serves enc conv AND reassembly)
    int R0 = ty * 2 - 2, C0 = tx * 8 - 2;
    for (int idx = tid; idx < 576; idx += 512) {
        int hp = idx >> 3, cq = idx & 7;
        int hy = hp / 12, hx = hp - hy * 12;
        int gr = R0 + hy, gc = C0 + hx;
        short8 v0 = {0,0,0,0,0,0,0,0}, v1 = {0,0,0,0,0,0,0,0};
        if ((unsigned)gr < 64u && (unsigned)gc < 64u) {
            const unsigned short* src = xt + (b * 4096 + gr * 64 + gc) * 128 + cq * 16;
            v0 = *(const short8*)src;
            v1 = *(const short8*)(src + 8);
        }
        *(short8*)&xs[hp * 136 + cq * 16]     = v0;
        *(short8*)&xs[hp * 136 + cq * 16 + 8] = v1;
    }
    __syncthreads();

    // ---- phase 2: encoder GEMM, M x K wave split (2 chains of 18 MFMAs each)
    int kp = w & 1, mg = w >> 1;
    int mf0 = mg * 2;
    bool two = (mg < 3);           // wave-uniform
    int ly = l15 >> 3, lx = l15 & 7;
    f32x4 acc0 = {0.f, 0.f, 0.f, 0.f}, acc1 = {0.f, 0.f, 0.f, 0.f};
#pragma unroll
    for (int kap = 0; kap < 9; ++kap) {
        int dy = kap / 3, dx = kap % 3;
        const unsigned short* xrow = &xs[((ly + dy + 1) * 12 + lx + dx + 1) * 136];
#pragma unroll
        for (int cc = 0; cc < 2; ++cc) {
            int cs = kp * 2 + cc;
            short8 bfrag = *(const short8*)&xrow[cs * 32 + kgrp * 8];
            const unsigned short* wrk = weffR + ((kap * 4 + cs) * 7 + mf0) * 512 + lane * 8;
            acc0 = __builtin_amdgcn_mfma_f32_16x16x32_bf16(
                *(const short8*)wrk, bfrag, acc0, 0, 0, 0);
            if (two)
                acc1 = __builtin_amdgcn_mfma_f32_16x16x32_bf16(
                    *(const short8*)(wrk + 512), bfrag, acc1, 0, 0, 0);
        }
    }
    // ---- phase 3: K-partials to psum
#pragma unroll
    for (int r = 0; r < 4; ++r) {
        int q0 = mf0 * 16 + kgrp * 4 + r;
        psum[(kp * 112 + q0) * 17 + l15] = acc0[r];
        if (two) psum[(kp * 112 + q0 + 16) * 17 + l15] = acc1[r];
    }
    __syncthreads();

    // ---- phase 4: reduce 2 K-halves + bias -> sm
    for (int idx = tid; idx < 1600; idx += 512) {
        int q = idx >> 4, lowpx = idx & 15;
        float v = psum[q * 17 + lowpx] + psum[(112 + q) * 17 + lowpx] + beff[q];
        sm[(q >> 2) * 64 + lowpx * 4 + (q & 3)] = v;
    }
    __syncthreads();

    // ---- phase 5: wave-parallel softmax over 25 k (8-lane groups, 512 thr)
    {
        int e = tid >> 3, kg = tid & 7;
        float v[4];
        float m = -1e30f;
#pragma unroll
        for (int j = 0; j < 4; ++j) {
            int k = kg + 8 * j;
            float val = (k < 25) ? sm[k * 64 + e] : -1e30f;
            v[j] = val; m = fmaxf(m, val);
        }
        m = fmaxf(m, __shfl_xor(m, 1));
        m = fmaxf(m, __shfl_xor(m, 2));
        m = fmaxf(m, __shfl_xor(m, 4));
        float s = 0.f;
#pragma unroll
        for (int j = 0; j < 4; ++j) {
            int k = kg + 8 * j;
            if (k < 25) { v[j] = __expf(v[j] - m); s += v[j]; }
        }
        s += __shfl_xor(s, 1);
        s += __shfl_xor(s, 2);
        s += __shfl_xor(s, 4);
        float inv = 1.f / s;
#pragma unroll
        for (int j = 0; j < 4; ++j) {
            int k = kg + 8 * j;
            if (k < 25) sm[k * 64 + e] = v[j] * inv;
        }
    }
    __syncthreads();

    // ---- phase 6: reassembly -> re (bf16, [p][136]); 4 channels per thread
    {
        int lowpx = tid & 15, cgrp = tid >> 4;   // cgrp 0..31 -> c = cgrp*4..+3
        int ly2 = lowpx >> 3, lx2 = lowpx & 7;
        float racc[4][4];
#pragma unroll
        for (int cc = 0; cc < 4; ++cc)
#pragma unroll
            for (int s = 0; s < 4; ++s) racc[cc][s] = 0.f;
#pragma unroll
        for (int k = 0; k < 25; ++k) {
            int i = k / 5, j = k % 5;
            float4 wk4 = *(const float4*)&sm[k * 64 + lowpx * 4];
            short4v tap4 = *(const short4v*)&xs[((ly2 + i) * 12 + (lx2 + j)) * 136 + cgrp * 4];
#pragma unroll
            for (int cc = 0; cc < 4; ++cc) {
                float tap = bf2f((unsigned short)tap4[cc]);
                racc[cc][0] += wk4.x * tap;
                racc[cc][1] += wk4.y * tap;
                racc[cc][2] += wk4.z * tap;
                racc[cc][3] += wk4.w * tap;
            }
        }
#pragma unroll
        for (int s = 0; s < 4; ++s) {
            int p = (ly2 * 2 + (s >> 1)) * 16 + lx2 * 2 + (s & 1);
            short4v pk;
#pragma unroll
            for (int cc = 0; cc < 4; ++cc) pk[cc] = (short)f2bf(racc[cc][s]);
            *(short4v*)&re[p * 136 + cgrp * 4] = pk;
        }
    }
    __syncthreads();

    // ---- phase 7: projection GEMM; wave w owns m-frag w (o = w*16..+15), all 4 n-frags
    f32x4 pacc[4];
#pragma unroll
    for (int nf = 0; nf < 4; ++nf) pacc[nf] = f32x4{0.f, 0.f, 0.f, 0.f};
#pragma unroll
    for (int cs = 0; cs < 4; ++cs) {
        short8 af = *(const short8*)(wpbR + (cs * 8 + w) * 512 + lane * 8);
#pragma unroll
        for (int nf = 0; nf < 4; ++nf) {
            short8 bfrag = *(const short8*)&re[(nf * 16 + l15) * 136 + cs * 32 + kgrp * 8];
            pacc[nf] = __builtin_amdgcn_mfma_f32_16x16x32_bf16(af, bfrag, pacc[nf], 0, 0, 0);
        }
    }
    // ---- phase 8: store
    float bo[4];
#pragma unroll
    for (int r = 0; r < 4; ++r) bo[r] = bproj[w * 16 + kgrp * 4 + r];
#pragma unroll
    for (int nf = 0; nf < 4; ++nf) {
        int hs = ty * 4 + nf;
        float* ob = out + (b * 128 + w * 16 + kgrp * 4) * 16384 + hs * 128 + tx * 16 + l15;
#pragma unroll
        for (int r = 0; r < 4; ++r)
            ob[r * 16384] = pacc[nf][r] + bo[r];
    }
}

extern "C" void kernel_launch(void* const* d_in, const int* in_sizes, int n_in,
                              void* d_out, int out_size, void* d_ws, size_t ws_size,
                              hipStream_t stream) {
    const float* x      = (const float*)d_in[0];
    const float* w_comp = (const float*)d_in[1];
    const float* b_comp = (const float*)d_in[2];
    const float* w_enc  = (const float*)d_in[3];
    const float* b_enc  = (const float*)d_in[4];
    const float* w_proj = (const float*)d_in[5];
    const float* b_proj = (const float*)d_in[6];
    float* out = (float*)d_out;

    char* base = (char*)d_ws;
    unsigned short* xt    = (unsigned short*)(base);              // 2,097,152 B
    unsigned short* weffR = (unsigned short*)(base + 2097152);    //   258,048 B (252*512*2)
    float*          beff  = (float*)         (base + 2355200);    //       512 B (128 f32)
    unsigned short* wpbR  = (unsigned short*)(base + 2355712);    //    32,768 B

    k_prep<<<625, 256, 0, stream>>>(x, w_enc, w_comp, b_enc, b_comp, w_proj,
                                    xt, weffR, beff, wpbR);
    k_main<<<512, 512, 0, stream>>>(xt, weffR, beff, wpbR, b_proj, out);
}